// Round 11
// baseline (207.632 us; speedup 1.0000x reference)
//
#include <hip/hip_runtime.h>
#include <math.h>

// HyperbolicMultiHeadAttention — round 11:
//  * split_all eliminated: GEMMs stage fp32 operands and convert to bf16
//    in-register (cvt_pk at LDS-store) — one fewer dispatch, −43MB HBM.
//  * gemm_qkv: 64x64 tile BK=64, fp32 A/B staging, launch_bounds(256,5).
//  * gemm_out: ccb bf16 A + fp32 Wo B staging.
//  * attn/combine unchanged (r10 structure: split-K x4, bf16 partials).
//  * Harness floor: ~50us of fill/restore per timed iteration (256MB ws
//    re-poison etc.) — not controllable from kernel_launch.
// B=2, S=1024, D=1024, H=16, dh=64.

#define EPS_ 1e-5f

constexpr int Ss = 1024, Dd = 1024, Hh = 16, DHh = 64;

typedef __attribute__((ext_vector_type(8))) short bf16x8;
typedef __attribute__((ext_vector_type(4))) short s16x4;
typedef __attribute__((ext_vector_type(4))) float f32x4;

__device__ __forceinline__ float softplusf_(float x) {
    return (x > 20.f) ? x : log1pf(expf(x));
}
__device__ __forceinline__ float waveSum64(float v) {
#pragma unroll
    for (int m = 32; m >= 1; m >>= 1) v += __shfl_xor(v, m, 64);
    return v;
}
__device__ __forceinline__ short f2bf(float f) {
    union { float f; unsigned u; } v; v.f = f;
    unsigned r = v.u + 0x7FFFu + ((v.u >> 16) & 1u);   // RNE
    return (short)(r >> 16);
}
__device__ __forceinline__ float bf2f(unsigned short h) {
    union { unsigned u; float f; } v; v.u = ((unsigned)h) << 16;
    return v.f;
}
__device__ __forceinline__ unsigned pks(short a, short b) {
    return (unsigned)(unsigned short)a | ((unsigned)(unsigned short)b << 16);
}

#if __has_builtin(__builtin_amdgcn_cvt_pk_bf16_f32)
typedef __attribute__((ext_vector_type(2))) __bf16 bfp2;
__device__ __forceinline__ unsigned cvtpk(float a, float b) {
    union { bfp2 v; unsigned u; } x;
    x.v = __builtin_amdgcn_cvt_pk_bf16_f32(a, b);
    return x.u;
}
#else
__device__ __forceinline__ unsigned cvtpk(float a, float b) { return pks(f2bf(a), f2bf(b)); }
#endif

#if __has_builtin(__builtin_amdgcn_sqrtf)
#define FSQRT __builtin_amdgcn_sqrtf
#else
#define FSQRT sqrtf
#endif
#if __has_builtin(__builtin_amdgcn_logf)
#define FLOG2 __builtin_amdgcn_logf
#else
#define FLOG2 __log2f
#endif
#if __has_builtin(__builtin_amdgcn_exp2f)
#define FEXP2 __builtin_amdgcn_exp2f
#else
#define FEXP2 exp2f
#endif

// convert 16 fp32 (4 x float4) -> 8 packed bf16 dwords, store as 2 x b128
__device__ __forceinline__ void cvt16_store(short* dst, const float4* v) {
    uint4 p0, p1;
    p0.x = cvtpk(v[0].x, v[0].y); p0.y = cvtpk(v[0].z, v[0].w);
    p0.z = cvtpk(v[1].x, v[1].y); p0.w = cvtpk(v[1].z, v[1].w);
    p1.x = cvtpk(v[2].x, v[2].y); p1.y = cvtpk(v[2].z, v[2].w);
    p1.z = cvtpk(v[3].x, v[3].y); p1.w = cvtpk(v[3].z, v[3].w);
    *(uint4*)dst = p0;
    *(uint4*)(dst + 8) = p1;
}

// ------------- QKV GEMM: 64x64 tile, BK=64, fp32 staging + fused maps -------------
// grid (16 colTiles=heads, 32 rowTiles, 3 z). Tile cols = exactly one head.
__global__ __launch_bounds__(256, 5) void gemm_qkv(
    const float* __restrict__ Ax,
    const float* __restrict__ Wq, const float* __restrict__ Wk, const float* __restrict__ Wv,
    short* __restrict__ qh, short* __restrict__ kh, short* __restrict__ vtT,
    float* __restrict__ qnsT, float2* __restrict__ knpk,
    const float* __restrict__ p_logc)
{
    const int z = blockIdx.z;
    const float* Bx = (z == 0) ? Wq : (z == 1 ? Wk : Wv);
    const int K = 1024;

    __shared__ short As[64 * 72];   // 64 rows x 64 k, stride 72 shorts
    __shared__ short Bs[64 * 72];

    const int tid = threadIdx.x;
    const int wv = tid >> 6, lane = tid & 63, quad = lane >> 4, l15 = lane & 15;
    const int bm = blockIdx.y * 64, bn = blockIdx.x * 64;
    const int sr = tid >> 2, sq = (tid & 3) * 16;

    const float* gA = Ax + (size_t)(bm + sr) * K + sq;
    const float* gB = Bx + (size_t)(bn + sr) * K + sq;

    f32x4 acc[4];
#pragma unroll
    for (int j = 0; j < 4; j++) acc[j] = (f32x4){0.f, 0.f, 0.f, 0.f};

    float4 aP[4], bP[4];
#pragma unroll
    for (int i = 0; i < 4; i++) {
        aP[i] = *(const float4*)(gA + i * 4);
        bP[i] = *(const float4*)(gB + i * 4);
    }

    for (int k0 = 0; k0 < K; k0 += 64) {
        __syncthreads();
        cvt16_store(&As[sr * 72 + sq], aP);
        cvt16_store(&Bs[sr * 72 + sq], bP);
        __syncthreads();
        if (k0 + 64 < K) {
#pragma unroll
            for (int i = 0; i < 4; i++) {
                aP[i] = *(const float4*)(gA + k0 + 64 + i * 4);
                bP[i] = *(const float4*)(gB + k0 + 64 + i * 4);
            }
        }
#pragma unroll
        for (int w = 0; w < 2; w++) {
            bf16x8 fa = *(const bf16x8*)&As[(wv * 16 + l15) * 72 + w * 32 + quad * 8];
#pragma unroll
            for (int nt = 0; nt < 4; nt++) {
                bf16x8 fb = *(const bf16x8*)&Bs[(nt * 16 + l15) * 72 + w * 32 + quad * 8];
                acc[nt] = __builtin_amdgcn_mfma_f32_16x16x32_bf16(fa, fb, acc[nt], 0, 0, 0);
            }
        }
    }

    // ---- fused epilogue (one head per tile) ----
    const float c = softplusf_(p_logc[0]);
    const float sc = sqrtf(c);
    const float twoC = 2.f * c;
    const int h0 = blockIdx.x;
    const int mbase = bm + wv * 16;

    if (z < 2) {
        short* yout = (z == 0) ? qh : kh;
        float fr[4];
#pragma unroll
        for (int r = 0; r < 4; r++) {
            float s2 = 0.f;
#pragma unroll
            for (int nt = 0; nt < 4; nt++) s2 += acc[nt][r] * acc[nt][r];
#pragma unroll
            for (int mk = 1; mk < 16; mk <<= 1) s2 += __shfl_xor(s2, mk, 64);
            float n = fmaxf(sqrtf(s2), EPS_);
            float fac = tanhf(sc * n) / (sc * n);
            fr[r] = fac;
            if (l15 == 0) {
                int m = mbase + quad * 4 + r;
                int bI = m >> 10, s = m & 1023;
                float yns = s2 * fac * fac;
                if (z == 0) {
                    qnsT[(size_t)(bI * Hh + h0) * Ss + s] = yns;
                } else {
                    knpk[(size_t)(bI * Hh + h0) * Ss + s]
                        = make_float2(yns, twoC / (1.f - c * yns));
                }
            }
        }
#pragma unroll
        for (int nt = 0; nt < 4; nt++)
#pragma unroll
            for (int r = 0; r < 4; r++) {
                int m = mbase + quad * 4 + r;
                yout[(size_t)m * Dd + bn + nt * 16 + l15] = f2bf(acc[nt][r] * fr[r]);
            }
    } else {
        float tr[4];
#pragma unroll
        for (int r = 0; r < 4; r++) {
            float s2 = 0.f;
#pragma unroll
            for (int nt = 0; nt < 4; nt++) s2 += acc[nt][r] * acc[nt][r];
#pragma unroll
            for (int mk = 1; mk < 16; mk <<= 1) s2 += __shfl_xor(s2, mk, 64);
            float n = fmaxf(sqrtf(s2), EPS_);
            float fac = tanhf(sc * n) / (sc * n);
            float yn = n * fac;
            float ycl = fminf(yn, 1.f / sc - EPS_);
            float f2 = atanhf(sc * ycl) / (sc * fmaxf(yn, EPS_));
            tr[r] = fac * f2;
        }
        const int m0 = mbase + quad * 4;
        const int bI = m0 >> 10, s0 = m0 & 1023;
#pragma unroll
        for (int nt = 0; nt < 4; nt++) {
            int d = nt * 16 + l15;
            uint2 pk;
            pk.x = cvtpk(acc[nt][0] * tr[0], acc[nt][1] * tr[1]);
            pk.y = cvtpk(acc[nt][2] * tr[2], acc[nt][3] * tr[3]);
            *(uint2*)&vtT[((size_t)(bI * Hh + h0) * DHh + d) * Ss + s0] = pk;
        }
    }
}

// ---------------- LDS-staged pipelined MFMA flash attention (split-K x4) ----------------
__global__ __launch_bounds__(256) void attn_mfma(
    const short* __restrict__ qh, const short* __restrict__ kh, const short* __restrict__ vtT,
    const float* __restrict__ qnsT, const float2* __restrict__ knpk,
    unsigned short* __restrict__ Opart, float* __restrict__ lpart,
    const float* __restrict__ p_logc, const float* __restrict__ p_beta)
{
    const float c = softplusf_(p_logc[0]);
    const float sc = sqrtf(c);
    const float bp = softplusf_(p_beta[0]);
    const float nkc = -bp / sc;          // p = u^(-bp/sc) = 2^(nkc * log2 u)
    const float cap = 2.f * c * 1e5f;    // = 2c / EPS-clamped denom
    const float onePlus = 1.f + EPS_;

    const int h = blockIdx.y, b = blockIdx.z;
    const int kr = blockIdx.x & 3, qt = blockIdx.x >> 2;
    const int tid = threadIdx.x;
    const int wv = tid >> 6, lane = tid & 63;
    const int quad = lane >> 4, l15 = lane & 15;
    const int bh = b * Hh + h;
    const int q = qt * 64 + wv * 16 + l15;

    __shared__ short Ks[64][72];   // [t][d]
    __shared__ short Vt[64][72];   // [d][t]

    const short* qb = qh + (size_t)(b * Ss + q) * Dd + h * DHh + quad * 8;
    bf16x8 qf0 = *(const bf16x8*)qb;
    bf16x8 qf1 = *(const bf16x8*)(qb + 32);

    const float qn = qnsT[(size_t)bh * Ss + q];
    const float irq = 1.f / (1.f - c * qn);

    f32x4 O4[4];
#pragma unroll
    for (int nt = 0; nt < 4; nt++) O4[nt] = (f32x4){0.f, 0.f, 0.f, 0.f};
    float lac = 0.f;

    const int tbase = kr * 256;
    const int sr = tid >> 2, sseg = (tid & 3) * 16;
    const short* kgp = kh + (size_t)(b * Ss + tbase + sr) * Dd + h * DHh + sseg;
    const short* vgp = vtT + ((size_t)bh * DHh + sr) * Ss + tbase + sseg;
    const float2* nb = knpk + (size_t)bh * Ss;

    bf16x8 kA0 = *(const bf16x8*)kgp;
    bf16x8 kA1 = *(const bf16x8*)(kgp + 8);
    bf16x8 vA0 = *(const bf16x8*)vgp;
    bf16x8 vA1 = *(const bf16x8*)(vgp + 8);

    for (int ch = 0; ch < 4; ch++) {
        const int t0 = tbase + ch * 64;

        __syncthreads();
        *(bf16x8*)&Ks[sr][sseg]     = kA0;
        *(bf16x8*)&Ks[sr][sseg + 8] = kA1;
        *(bf16x8*)&Vt[sr][sseg]     = vA0;
        *(bf16x8*)&Vt[sr][sseg + 8] = vA1;
        __syncthreads();

        if (ch < 3) {
            kA0 = *(const bf16x8*)(kgp + (size_t)((ch + 1) * 64) * Dd);
            kA1 = *(const bf16x8*)(kgp + (size_t)((ch + 1) * 64) * Dd + 8);
            vA0 = *(const bf16x8*)(vgp + (ch + 1) * 64);
            vA1 = *(const bf16x8*)(vgp + (ch + 1) * 64 + 8);
        }

        // S^T = K * Q^T
        f32x4 acc[4];
#pragma unroll
        for (int nt = 0; nt < 4; nt++) {
            bf16x8 k0 = *(const bf16x8*)&Ks[nt * 16 + l15][quad * 8];
            bf16x8 k1 = *(const bf16x8*)&Ks[nt * 16 + l15][32 + quad * 8];
            f32x4 a = (f32x4){0.f, 0.f, 0.f, 0.f};
            a = __builtin_amdgcn_mfma_f32_16x16x32_bf16(k0, qf0, a, 0, 0, 0);
            a = __builtin_amdgcn_mfma_f32_16x16x32_bf16(k1, qf1, a, 0, 0, 0);
            acc[nt] = a;
        }

        // scores (lane: t = nt*16 + quad*4 + r, q = l15)
        float sv[4][4];
#pragma unroll
        for (int nt = 0; nt < 4; nt++) {
            const float2* np = nb + t0 + nt * 16 + quad * 4;
            f32x4 n0 = *(const f32x4*)np;
            f32x4 n1 = *(const f32x4*)(np + 2);
#pragma unroll
            for (int r = 0; r < 4; r++) {
                float kn   = (r < 2) ? n0[(r & 1) * 2]     : n1[(r & 1) * 2];
                float ik2c = (r < 2) ? n0[(r & 1) * 2 + 1] : n1[(r & 1) * 2 + 1];
                float dns = (qn + kn) - 2.f * acc[nt][r];
                float co  = fminf(irq * ik2c, cap);
                float arg = fmaxf(fmaf(co, dns, 1.f), onePlus);
                float u   = arg + FSQRT(fmaf(arg, arg, -1.f));
                float p   = FEXP2(nkc * FLOG2(u));
                sv[nt][r] = p;
                lac += p;
            }
        }

        union { unsigned u[4]; bf16x8 v; } p0, p1;
        p0.u[0] = cvtpk(sv[0][0], sv[0][1]); p0.u[1] = cvtpk(sv[0][2], sv[0][3]);
        p0.u[2] = cvtpk(sv[1][0], sv[1][1]); p0.u[3] = cvtpk(sv[1][2], sv[1][3]);
        p1.u[0] = cvtpk(sv[2][0], sv[2][1]); p1.u[1] = cvtpk(sv[2][2], sv[2][3]);
        p1.u[2] = cvtpk(sv[3][0], sv[3][1]); p1.u[3] = cvtpk(sv[3][2], sv[3][3]);

        // O^T += V^T * P^T
#pragma unroll
        for (int nt = 0; nt < 4; nt++) {
            const short* vr = &Vt[nt * 16 + l15][quad * 4];
            s16x4 a0 = *(const s16x4*)(vr);
            s16x4 a1 = *(const s16x4*)(vr + 16);
            s16x4 a2 = *(const s16x4*)(vr + 32);
            s16x4 a3 = *(const s16x4*)(vr + 48);
            bf16x8 v0 = __builtin_shufflevector(a0, a1, 0, 1, 2, 3, 4, 5, 6, 7);
            bf16x8 v1 = __builtin_shufflevector(a2, a3, 0, 1, 2, 3, 4, 5, 6, 7);
            O4[nt] = __builtin_amdgcn_mfma_f32_16x16x32_bf16(v0, p0.v, O4[nt], 0, 0, 0);
            O4[nt] = __builtin_amdgcn_mfma_f32_16x16x32_bf16(v1, p1.v, O4[nt], 0, 0, 0);
        }
    }

    lac += __shfl_xor(lac, 16, 64);
    lac += __shfl_xor(lac, 32, 64);
    unsigned short* ob = Opart + (((size_t)bh * 4 + kr) * Ss + q) * DHh;
#pragma unroll
    for (int nt = 0; nt < 4; nt++) {
        uint2 pk;
        pk.x = cvtpk(O4[nt][0], O4[nt][1]);
        pk.y = cvtpk(O4[nt][2], O4[nt][3]);
        *(uint2*)(ob + nt * 16 + quad * 4) = pk;
    }
    if (lane < 16)
        lpart[((size_t)bh * 4 + kr) * Ss + qt * 64 + wv * 16 + lane] = lac;
}

// ---------------- combine 4 split-K partials + exp/log-map epilogue ----------------
__global__ __launch_bounds__(256) void attn_combine(
    const unsigned short* __restrict__ Opart, const float* __restrict__ lpart,
    short* __restrict__ ccb, const float* __restrict__ p_logc)
{
    const float c = softplusf_(p_logc[0]);
    const float sc = sqrtf(c);
    const int wv = threadIdx.x >> 6, d = threadIdx.x & 63;
    const int task = blockIdx.x * 4 + wv;        // bh*1024 + s
    const int bh = task >> 10, s = task & 1023;

    float O = 0.f, l = 0.f;
#pragma unroll
    for (int k = 0; k < 4; k++) {
        O += bf2f(Opart[(((size_t)bh * 4 + k) * Ss + s) * DHh + d]);
        l += lpart[((size_t)bh * 4 + k) * Ss + s];
    }
    float ot = O / l;

    float t2 = waveSum64(ot * ot);
    float n = fmaxf(sqrtf(t2), EPS_);
    float fac = tanhf(sc * n) / (sc * n);          // exp_map
    float y2 = t2 * fac * fac;
    float yn = fmaxf(sqrtf(y2), EPS_);
    float ycl = fminf(yn, 1.f / sc - EPS_);
    float fac2 = atanhf(sc * ycl) / (sc * yn);     // log_map
    float tot = fac * fac2;

    int b = bh >> 4, hh = bh & 15;
    ccb[(size_t)(b * Ss + s) * Dd + hh * DHh + d] = f2bf(ot * tot);
}

// ---------------- output projection: 64x64 tile, BK=64, fp32 Wo staging ----------------
__global__ __launch_bounds__(256, 6) void gemm_out(
    const short* __restrict__ Ap, const float* __restrict__ Bx,
    float* __restrict__ Cp)
{
    const int K = 1024, N = 1024;
    __shared__ short As[64 * 72];
    __shared__ short Bs[64 * 72];
    const int tid = threadIdx.x;
    const int wv = tid >> 6, lane = tid & 63, quad = lane >> 4, l15 = lane & 15;
    const int bm = blockIdx.y * 64, bn = blockIdx.x * 64;
    const int sr = tid >> 2, sq = (tid & 3) * 16;

    const short* gA = Ap + (size_t)(bm + sr) * K + sq;
    const float* gB = Bx + (size_t)(bn + sr) * K + sq;

    f32x4 acc[4];
#pragma unroll
    for (int j = 0; j < 4; j++) acc[j] = (f32x4){0.f, 0.f, 0.f, 0.f};

    bf16x8 a0 = *(const bf16x8*)gA;
    bf16x8 a1 = *(const bf16x8*)(gA + 8);
    float4 bP[4];
#pragma unroll
    for (int i = 0; i < 4; i++) bP[i] = *(const float4*)(gB + i * 4);

    for (int k0 = 0; k0 < K; k0 += 64) {
        __syncthreads();
        *(bf16x8*)&As[sr * 72 + sq]     = a0;
        *(bf16x8*)&As[sr * 72 + sq + 8] = a1;
        cvt16_store(&Bs[sr * 72 + sq], bP);
        __syncthreads();
        if (k0 + 64 < K) {
            a0 = *(const bf16x8*)(gA + k0 + 64);
            a1 = *(const bf16x8*)(gA + k0 + 64 + 8);
#pragma unroll
            for (int i = 0; i < 4; i++) bP[i] = *(const float4*)(gB + k0 + 64 + i * 4);
        }
#pragma unroll
        for (int w = 0; w < 2; w++) {
            bf16x8 fa = *(const bf16x8*)&As[(wv * 16 + l15) * 72 + w * 32 + quad * 8];
#pragma unroll
            for (int nt = 0; nt < 4; nt++) {
                bf16x8 fb = *(const bf16x8*)&Bs[(nt * 16 + l15) * 72 + w * 32 + quad * 8];
                acc[nt] = __builtin_amdgcn_mfma_f32_16x16x32_bf16(fa, fb, acc[nt], 0, 0, 0);
            }
        }
    }
#pragma unroll
    for (int nt = 0; nt < 4; nt++)
#pragma unroll
        for (int r = 0; r < 4; r++)
            Cp[(size_t)(bm + wv * 16 + quad * 4 + r) * N + bn + nt * 16 + l15] = acc[nt][r];
}

extern "C" void kernel_launch(void* const* d_in, const int* in_sizes, int n_in,
                              void* d_out, int out_size, void* d_ws, size_t ws_size,
                              hipStream_t stream)
{
    const float* x    = (const float*)d_in[0];
    const float* Wq   = (const float*)d_in[1];
    const float* Wk   = (const float*)d_in[2];
    const float* Wv   = (const float*)d_in[3];
    const float* Wo   = (const float*)d_in[4];
    const float* logc = (const float*)d_in[5];
    const float* beta = (const float*)d_in[6];
    float* out = (float*)d_out;

    const size_t M2 = 2097152;
    short* ws    = (short*)d_ws;
    short* qh    = ws;                 // 2M shorts each
    short* kh    = qh + M2;
    short* vtT   = kh + M2;
    short* ccb   = vtT + M2;
    float* qnsT  = (float*)(ccb + M2);        // 32K floats
    float2* knpk = (float2*)(qnsT + 32768);   // 32K float2
    float* lpart = (float*)(knpk + 32768);    // 128K floats
    unsigned short* Opart = (unsigned short*)(lpart + 131072);  // 8M bf16 (16MB)

    // 1) QKV projection (fp32 staging, in-register bf16 cvt) + fused maps
    gemm_qkv<<<dim3(16, 32, 3), 256, 0, stream>>>(x, Wq, Wk, Wv,
        qh, kh, vtT, qnsT, knpk, logc);
    // 2) pipelined LDS-staged flash attention, split-K x4
    attn_mfma<<<dim3(64, 16, 2), 256, 0, stream>>>(qh, kh, vtT, qnsT, knpk,
        Opart, lpart, logc, beta);
    // 3) combine partials + exp/log maps -> bf16 concat
    attn_combine<<<dim3(8192), 256, 0, stream>>>(Opart, lpart, ccb, logc);
    // 4) output projection (fp32 Wo staging)
    gemm_out<<<dim3(16, 32), 256, 0, stream>>>(ccb, Wo, out);
}

// Round 12
// 181.448 us; speedup vs baseline: 1.1443x; 1.1443x over previous
//
#include <hip/hip_runtime.h>
#include <math.h>

// HyperbolicMultiHeadAttention — round 12 (revert to r10's proven 181us):
//  * split_all restored: bf16 pre-conversion keeps GEMM operand streams
//    half-width and L3-warm right before use. r11's in-GEMM fp32 staging
//    caused 5x HBM fetch amplification (100MB vs 20MB) because the harness's
//    256MB ws poison-fill wipes L3 every iteration.
//  * GEMMs: 64x64 tile, BK=64, bf16 staging, 6 blocks/CU.
//  * attn: split-K x4, LDS-staged, lean log-space score math, bf16 partials.
// B=2, S=1024, D=1024, H=16, dh=64.

#define EPS_ 1e-5f

constexpr int Ss = 1024, Dd = 1024, Hh = 16, DHh = 64;

typedef __attribute__((ext_vector_type(8))) short bf16x8;
typedef __attribute__((ext_vector_type(4))) short s16x4;
typedef __attribute__((ext_vector_type(4))) float f32x4;

__device__ __forceinline__ float softplusf_(float x) {
    return (x > 20.f) ? x : log1pf(expf(x));
}
__device__ __forceinline__ float waveSum64(float v) {
#pragma unroll
    for (int m = 32; m >= 1; m >>= 1) v += __shfl_xor(v, m, 64);
    return v;
}
__device__ __forceinline__ short f2bf(float f) {
    union { float f; unsigned u; } v; v.f = f;
    unsigned r = v.u + 0x7FFFu + ((v.u >> 16) & 1u);   // RNE
    return (short)(r >> 16);
}
__device__ __forceinline__ float bf2f(unsigned short h) {
    union { unsigned u; float f; } v; v.u = ((unsigned)h) << 16;
    return v.f;
}
__device__ __forceinline__ unsigned pks(short a, short b) {
    return (unsigned)(unsigned short)a | ((unsigned)(unsigned short)b << 16);
}

#if __has_builtin(__builtin_amdgcn_cvt_pk_bf16_f32)
typedef __attribute__((ext_vector_type(2))) __bf16 bfp2;
__device__ __forceinline__ unsigned cvtpk(float a, float b) {
    union { bfp2 v; unsigned u; } x;
    x.v = __builtin_amdgcn_cvt_pk_bf16_f32(a, b);
    return x.u;
}
#else
__device__ __forceinline__ unsigned cvtpk(float a, float b) { return pks(f2bf(a), f2bf(b)); }
#endif

#if __has_builtin(__builtin_amdgcn_sqrtf)
#define FSQRT __builtin_amdgcn_sqrtf
#else
#define FSQRT sqrtf
#endif
#if __has_builtin(__builtin_amdgcn_logf)
#define FLOG2 __builtin_amdgcn_logf
#else
#define FLOG2 __log2f
#endif
#if __has_builtin(__builtin_amdgcn_exp2f)
#define FEXP2 __builtin_amdgcn_exp2f
#else
#define FEXP2 exp2f
#endif

// ---------------- fp32 -> bf16 conversion (x, Wq, Wk, Wv, Wo) ----------------
__global__ __launch_bounds__(256) void split_all(
    const float* __restrict__ x,  const float* __restrict__ Wq,
    const float* __restrict__ Wk, const float* __restrict__ Wv,
    const float* __restrict__ Wo,
    short* __restrict__ xh,  short* __restrict__ wqh,
    short* __restrict__ wkh, short* __restrict__ wvh, short* __restrict__ woh)
{
    int g = blockIdx.x * 256 + threadIdx.x;
    const float* src; short* dst; int base;
    if (g < 524288)       { src = x;  dst = xh;  base = g; }
    else if (g < 786432)  { src = Wq; dst = wqh; base = g - 524288; }
    else if (g < 1048576) { src = Wk; dst = wkh; base = g - 786432; }
    else if (g < 1310720) { src = Wv; dst = wvh; base = g - 1048576; }
    else                  { src = Wo; dst = woh; base = g - 1310720; }
    float4 v = *(const float4*)(src + (size_t)base * 4);
    uint2 hp; hp.x = cvtpk(v.x, v.y); hp.y = cvtpk(v.z, v.w);
    *(uint2*)(dst + (size_t)base * 4) = hp;
}

// ------------- QKV GEMM: 64x64 tile, BK=64, 4 waves x 16 rows + fused maps -------------
// grid (16 colTiles=heads, 32 rowTiles, 3 z). Tile cols = exactly one head.
__global__ __launch_bounds__(256, 6) void gemm_qkv(
    const short* __restrict__ Ap,
    const short* __restrict__ Wq, const short* __restrict__ Wk, const short* __restrict__ Wv,
    short* __restrict__ qh, short* __restrict__ kh, short* __restrict__ vtT,
    float* __restrict__ qnsT, float2* __restrict__ knpk,
    const float* __restrict__ p_logc)
{
    const int z = blockIdx.z;
    const short* Bp = (z == 0) ? Wq : (z == 1 ? Wk : Wv);
    const int K = 1024;

    __shared__ short As[64 * 72];   // 64 rows x 64 k, stride 72 shorts
    __shared__ short Bs[64 * 72];

    const int tid = threadIdx.x;
    const int wv = tid >> 6, lane = tid & 63, quad = lane >> 4, l15 = lane & 15;
    const int bm = blockIdx.y * 64, bn = blockIdx.x * 64;
    const int sr = tid >> 2, sq = (tid & 3) * 16;

    const short* gA = Ap + (size_t)(bm + sr) * K + sq;
    const short* gB = Bp + (size_t)(bn + sr) * K + sq;

    f32x4 acc[4];
#pragma unroll
    for (int j = 0; j < 4; j++) acc[j] = (f32x4){0.f, 0.f, 0.f, 0.f};

    bf16x8 a0 = *(const bf16x8*)gA;
    bf16x8 a1 = *(const bf16x8*)(gA + 8);
    bf16x8 b0 = *(const bf16x8*)gB;
    bf16x8 b1 = *(const bf16x8*)(gB + 8);

    for (int k0 = 0; k0 < K; k0 += 64) {
        __syncthreads();
        *(bf16x8*)&As[sr * 72 + sq]     = a0;
        *(bf16x8*)&As[sr * 72 + sq + 8] = a1;
        *(bf16x8*)&Bs[sr * 72 + sq]     = b0;
        *(bf16x8*)&Bs[sr * 72 + sq + 8] = b1;
        __syncthreads();
        if (k0 + 64 < K) {
            a0 = *(const bf16x8*)(gA + k0 + 64);
            a1 = *(const bf16x8*)(gA + k0 + 64 + 8);
            b0 = *(const bf16x8*)(gB + k0 + 64);
            b1 = *(const bf16x8*)(gB + k0 + 64 + 8);
        }
#pragma unroll
        for (int w = 0; w < 2; w++) {
            bf16x8 fa = *(const bf16x8*)&As[(wv * 16 + l15) * 72 + w * 32 + quad * 8];
#pragma unroll
            for (int nt = 0; nt < 4; nt++) {
                bf16x8 fb = *(const bf16x8*)&Bs[(nt * 16 + l15) * 72 + w * 32 + quad * 8];
                acc[nt] = __builtin_amdgcn_mfma_f32_16x16x32_bf16(fa, fb, acc[nt], 0, 0, 0);
            }
        }
    }

    // ---- fused epilogue (one head per tile) ----
    const float c = softplusf_(p_logc[0]);
    const float sc = sqrtf(c);
    const float twoC = 2.f * c;
    const int h0 = blockIdx.x;
    const int mbase = bm + wv * 16;

    if (z < 2) {
        short* yout = (z == 0) ? qh : kh;
        float fr[4];
#pragma unroll
        for (int r = 0; r < 4; r++) {
            float s2 = 0.f;
#pragma unroll
            for (int nt = 0; nt < 4; nt++) s2 += acc[nt][r] * acc[nt][r];
#pragma unroll
            for (int mk = 1; mk < 16; mk <<= 1) s2 += __shfl_xor(s2, mk, 64);
            float n = fmaxf(sqrtf(s2), EPS_);
            float fac = tanhf(sc * n) / (sc * n);
            fr[r] = fac;
            if (l15 == 0) {
                int m = mbase + quad * 4 + r;
                int bI = m >> 10, s = m & 1023;
                float yns = s2 * fac * fac;
                if (z == 0) {
                    qnsT[(size_t)(bI * Hh + h0) * Ss + s] = yns;
                } else {
                    knpk[(size_t)(bI * Hh + h0) * Ss + s]
                        = make_float2(yns, twoC / (1.f - c * yns));
                }
            }
        }
#pragma unroll
        for (int nt = 0; nt < 4; nt++)
#pragma unroll
            for (int r = 0; r < 4; r++) {
                int m = mbase + quad * 4 + r;
                yout[(size_t)m * Dd + bn + nt * 16 + l15] = f2bf(acc[nt][r] * fr[r]);
            }
    } else {
        float tr[4];
#pragma unroll
        for (int r = 0; r < 4; r++) {
            float s2 = 0.f;
#pragma unroll
            for (int nt = 0; nt < 4; nt++) s2 += acc[nt][r] * acc[nt][r];
#pragma unroll
            for (int mk = 1; mk < 16; mk <<= 1) s2 += __shfl_xor(s2, mk, 64);
            float n = fmaxf(sqrtf(s2), EPS_);
            float fac = tanhf(sc * n) / (sc * n);
            float yn = n * fac;
            float ycl = fminf(yn, 1.f / sc - EPS_);
            float f2 = atanhf(sc * ycl) / (sc * fmaxf(yn, EPS_));
            tr[r] = fac * f2;
        }
        const int m0 = mbase + quad * 4;
        const int bI = m0 >> 10, s0 = m0 & 1023;
#pragma unroll
        for (int nt = 0; nt < 4; nt++) {
            int d = nt * 16 + l15;
            uint2 pk;
            pk.x = cvtpk(acc[nt][0] * tr[0], acc[nt][1] * tr[1]);
            pk.y = cvtpk(acc[nt][2] * tr[2], acc[nt][3] * tr[3]);
            *(uint2*)&vtT[((size_t)(bI * Hh + h0) * DHh + d) * Ss + s0] = pk;
        }
    }
}

// ---------------- LDS-staged pipelined MFMA flash attention (split-K x4) ----------------
__global__ __launch_bounds__(256) void attn_mfma(
    const short* __restrict__ qh, const short* __restrict__ kh, const short* __restrict__ vtT,
    const float* __restrict__ qnsT, const float2* __restrict__ knpk,
    unsigned short* __restrict__ Opart, float* __restrict__ lpart,
    const float* __restrict__ p_logc, const float* __restrict__ p_beta)
{
    const float c = softplusf_(p_logc[0]);
    const float sc = sqrtf(c);
    const float bp = softplusf_(p_beta[0]);
    const float nkc = -bp / sc;          // p = u^(-bp/sc) = 2^(nkc * log2 u)
    const float cap = 2.f * c * 1e5f;    // = 2c / EPS-clamped denom
    const float onePlus = 1.f + EPS_;

    const int h = blockIdx.y, b = blockIdx.z;
    const int kr = blockIdx.x & 3, qt = blockIdx.x >> 2;
    const int tid = threadIdx.x;
    const int wv = tid >> 6, lane = tid & 63;
    const int quad = lane >> 4, l15 = lane & 15;
    const int bh = b * Hh + h;
    const int q = qt * 64 + wv * 16 + l15;

    __shared__ short Ks[64][72];   // [t][d]
    __shared__ short Vt[64][72];   // [d][t]

    const short* qb = qh + (size_t)(b * Ss + q) * Dd + h * DHh + quad * 8;
    bf16x8 qf0 = *(const bf16x8*)qb;
    bf16x8 qf1 = *(const bf16x8*)(qb + 32);

    const float qn = qnsT[(size_t)bh * Ss + q];
    const float irq = 1.f / (1.f - c * qn);

    f32x4 O4[4];
#pragma unroll
    for (int nt = 0; nt < 4; nt++) O4[nt] = (f32x4){0.f, 0.f, 0.f, 0.f};
    float lac = 0.f;

    const int tbase = kr * 256;
    const int sr = tid >> 2, sseg = (tid & 3) * 16;
    const short* kgp = kh + (size_t)(b * Ss + tbase + sr) * Dd + h * DHh + sseg;
    const short* vgp = vtT + ((size_t)bh * DHh + sr) * Ss + tbase + sseg;
    const float2* nb = knpk + (size_t)bh * Ss;

    bf16x8 kA0 = *(const bf16x8*)kgp;
    bf16x8 kA1 = *(const bf16x8*)(kgp + 8);
    bf16x8 vA0 = *(const bf16x8*)vgp;
    bf16x8 vA1 = *(const bf16x8*)(vgp + 8);

    for (int ch = 0; ch < 4; ch++) {
        const int t0 = tbase + ch * 64;

        __syncthreads();
        *(bf16x8*)&Ks[sr][sseg]     = kA0;
        *(bf16x8*)&Ks[sr][sseg + 8] = kA1;
        *(bf16x8*)&Vt[sr][sseg]     = vA0;
        *(bf16x8*)&Vt[sr][sseg + 8] = vA1;
        __syncthreads();

        if (ch < 3) {
            kA0 = *(const bf16x8*)(kgp + (size_t)((ch + 1) * 64) * Dd);
            kA1 = *(const bf16x8*)(kgp + (size_t)((ch + 1) * 64) * Dd + 8);
            vA0 = *(const bf16x8*)(vgp + (ch + 1) * 64);
            vA1 = *(const bf16x8*)(vgp + (ch + 1) * 64 + 8);
        }

        // S^T = K * Q^T
        f32x4 acc[4];
#pragma unroll
        for (int nt = 0; nt < 4; nt++) {
            bf16x8 k0 = *(const bf16x8*)&Ks[nt * 16 + l15][quad * 8];
            bf16x8 k1 = *(const bf16x8*)&Ks[nt * 16 + l15][32 + quad * 8];
            f32x4 a = (f32x4){0.f, 0.f, 0.f, 0.f};
            a = __builtin_amdgcn_mfma_f32_16x16x32_bf16(k0, qf0, a, 0, 0, 0);
            a = __builtin_amdgcn_mfma_f32_16x16x32_bf16(k1, qf1, a, 0, 0, 0);
            acc[nt] = a;
        }

        // scores (lane: t = nt*16 + quad*4 + r, q = l15)
        float sv[4][4];
#pragma unroll
        for (int nt = 0; nt < 4; nt++) {
            const float2* np = nb + t0 + nt * 16 + quad * 4;
            f32x4 n0 = *(const f32x4*)np;
            f32x4 n1 = *(const f32x4*)(np + 2);
#pragma unroll
            for (int r = 0; r < 4; r++) {
                float kn   = (r < 2) ? n0[(r & 1) * 2]     : n1[(r & 1) * 2];
                float ik2c = (r < 2) ? n0[(r & 1) * 2 + 1] : n1[(r & 1) * 2 + 1];
                float dns = (qn + kn) - 2.f * acc[nt][r];
                float co  = fminf(irq * ik2c, cap);
                float arg = fmaxf(fmaf(co, dns, 1.f), onePlus);
                float u   = arg + FSQRT(fmaf(arg, arg, -1.f));
                float p   = FEXP2(nkc * FLOG2(u));
                sv[nt][r] = p;
                lac += p;
            }
        }

        union { unsigned u[4]; bf16x8 v; } p0, p1;
        p0.u[0] = cvtpk(sv[0][0], sv[0][1]); p0.u[1] = cvtpk(sv[0][2], sv[0][3]);
        p0.u[2] = cvtpk(sv[1][0], sv[1][1]); p0.u[3] = cvtpk(sv[1][2], sv[1][3]);
        p1.u[0] = cvtpk(sv[2][0], sv[2][1]); p1.u[1] = cvtpk(sv[2][2], sv[2][3]);
        p1.u[2] = cvtpk(sv[3][0], sv[3][1]); p1.u[3] = cvtpk(sv[3][2], sv[3][3]);

        // O^T += V^T * P^T
#pragma unroll
        for (int nt = 0; nt < 4; nt++) {
            const short* vr = &Vt[nt * 16 + l15][quad * 4];
            s16x4 a0 = *(const s16x4*)(vr);
            s16x4 a1 = *(const s16x4*)(vr + 16);
            s16x4 a2 = *(const s16x4*)(vr + 32);
            s16x4 a3 = *(const s16x4*)(vr + 48);
            bf16x8 v0 = __builtin_shufflevector(a0, a1, 0, 1, 2, 3, 4, 5, 6, 7);
            bf16x8 v1 = __builtin_shufflevector(a2, a3, 0, 1, 2, 3, 4, 5, 6, 7);
            O4[nt] = __builtin_amdgcn_mfma_f32_16x16x32_bf16(v0, p0.v, O4[nt], 0, 0, 0);
            O4[nt] = __builtin_amdgcn_mfma_f32_16x16x32_bf16(v1, p1.v, O4[nt], 0, 0, 0);
        }
    }

    lac += __shfl_xor(lac, 16, 64);
    lac += __shfl_xor(lac, 32, 64);
    unsigned short* ob = Opart + (((size_t)bh * 4 + kr) * Ss + q) * DHh;
#pragma unroll
    for (int nt = 0; nt < 4; nt++) {
        uint2 pk;
        pk.x = cvtpk(O4[nt][0], O4[nt][1]);
        pk.y = cvtpk(O4[nt][2], O4[nt][3]);
        *(uint2*)(ob + nt * 16 + quad * 4) = pk;
    }
    if (lane < 16)
        lpart[((size_t)bh * 4 + kr) * Ss + qt * 64 + wv * 16 + lane] = lac;
}

// ---------------- combine 4 split-K partials + exp/log-map epilogue ----------------
__global__ __launch_bounds__(256) void attn_combine(
    const unsigned short* __restrict__ Opart, const float* __restrict__ lpart,
    short* __restrict__ ccb, const float* __restrict__ p_logc)
{
    const float c = softplusf_(p_logc[0]);
    const float sc = sqrtf(c);
    const int wv = threadIdx.x >> 6, d = threadIdx.x & 63;
    const int task = blockIdx.x * 4 + wv;        // bh*1024 + s
    const int bh = task >> 10, s = task & 1023;

    float O = 0.f, l = 0.f;
#pragma unroll
    for (int k = 0; k < 4; k++) {
        O += bf2f(Opart[(((size_t)bh * 4 + k) * Ss + s) * DHh + d]);
        l += lpart[((size_t)bh * 4 + k) * Ss + s];
    }
    float ot = O / l;

    float t2 = waveSum64(ot * ot);
    float n = fmaxf(sqrtf(t2), EPS_);
    float fac = tanhf(sc * n) / (sc * n);          // exp_map
    float y2 = t2 * fac * fac;
    float yn = fmaxf(sqrtf(y2), EPS_);
    float ycl = fminf(yn, 1.f / sc - EPS_);
    float fac2 = atanhf(sc * ycl) / (sc * yn);     // log_map
    float tot = fac * fac2;

    int b = bh >> 4, hh = bh & 15;
    ccb[(size_t)(b * Ss + s) * Dd + hh * DHh + d] = f2bf(ot * tot);
}

// ---------------- output projection: 64x64 tile, BK=64 ----------------
__global__ __launch_bounds__(256, 6) void gemm_out(
    const short* __restrict__ Ap, const short* __restrict__ Bp,
    float* __restrict__ Cp)
{
    const int K = 1024, N = 1024;
    __shared__ short As[64 * 72];
    __shared__ short Bs[64 * 72];
    const int tid = threadIdx.x;
    const int wv = tid >> 6, lane = tid & 63, quad = lane >> 4, l15 = lane & 15;
    const int bm = blockIdx.y * 64, bn = blockIdx.x * 64;
    const int sr = tid >> 2, sq = (tid & 3) * 16;

    const short* gA = Ap + (size_t)(bm + sr) * K + sq;
    const short* gB = Bp + (size_t)(bn + sr) * K + sq;

    f32x4 acc[4];
#pragma unroll
    for (int j = 0; j < 4; j++) acc[j] = (f32x4){0.f, 0.f, 0.f, 0.f};

    bf16x8 a0 = *(const bf16x8*)gA;
    bf16x8 a1 = *(const bf16x8*)(gA + 8);
    bf16x8 b0 = *(const bf16x8*)gB;
    bf16x8 b1 = *(const bf16x8*)(gB + 8);

    for (int k0 = 0; k0 < K; k0 += 64) {
        __syncthreads();
        *(bf16x8*)&As[sr * 72 + sq]     = a0;
        *(bf16x8*)&As[sr * 72 + sq + 8] = a1;
        *(bf16x8*)&Bs[sr * 72 + sq]     = b0;
        *(bf16x8*)&Bs[sr * 72 + sq + 8] = b1;
        __syncthreads();
        if (k0 + 64 < K) {
            a0 = *(const bf16x8*)(gA + k0 + 64);
            a1 = *(const bf16x8*)(gA + k0 + 64 + 8);
            b0 = *(const bf16x8*)(gB + k0 + 64);
            b1 = *(const bf16x8*)(gB + k0 + 64 + 8);
        }
#pragma unroll
        for (int w = 0; w < 2; w++) {
            bf16x8 fa = *(const bf16x8*)&As[(wv * 16 + l15) * 72 + w * 32 + quad * 8];
#pragma unroll
            for (int nt = 0; nt < 4; nt++) {
                bf16x8 fb = *(const bf16x8*)&Bs[(nt * 16 + l15) * 72 + w * 32 + quad * 8];
                acc[nt] = __builtin_amdgcn_mfma_f32_16x16x32_bf16(fa, fb, acc[nt], 0, 0, 0);
            }
        }
    }
#pragma unroll
    for (int nt = 0; nt < 4; nt++)
#pragma unroll
        for (int r = 0; r < 4; r++)
            Cp[(size_t)(bm + wv * 16 + quad * 4 + r) * N + bn + nt * 16 + l15] = acc[nt][r];
}

extern "C" void kernel_launch(void* const* d_in, const int* in_sizes, int n_in,
                              void* d_out, int out_size, void* d_ws, size_t ws_size,
                              hipStream_t stream)
{
    const float* x    = (const float*)d_in[0];
    const float* Wq   = (const float*)d_in[1];
    const float* Wk   = (const float*)d_in[2];
    const float* Wv   = (const float*)d_in[3];
    const float* Wo   = (const float*)d_in[4];
    const float* logc = (const float*)d_in[5];
    const float* beta = (const float*)d_in[6];
    float* out = (float*)d_out;

    const size_t M2 = 2097152, M1 = 1048576;
    short* ws    = (short*)d_ws;
    short* xh    = ws;                 // 2M shorts (dead after gemm_qkv; ccb aliases)
    short* wqh   = xh + M2;            // 1M each
    short* wkh   = wqh + M1;
    short* wvh   = wkh + M1;
    short* woh   = wvh + M1;
    short* qh    = woh + M1;           // 2M each
    short* kh    = qh + M2;
    short* vtT   = kh + M2;
    float* qnsT  = (float*)(vtT + M2); // 32K floats
    float2* knpk = (float2*)(qnsT + 32768);   // 32K float2
    float* lpart = (float*)(knpk + 32768);    // 128K floats
    unsigned short* Opart = (unsigned short*)(lpart + 131072);  // 8M bf16 (16MB)
    short* ccb   = xh;                 // alias (xh dead after gemm_qkv)

    // 1) fp32 -> bf16
    split_all<<<dim3(6144), 256, 0, stream>>>(x, Wq, Wk, Wv, Wo, xh, wqh, wkh, wvh, woh);
    // 2) QKV projection + fused hyperbolic maps / packed key table (6 blocks/CU)
    gemm_qkv<<<dim3(16, 32, 3), 256, 0, stream>>>(xh, wqh, wkh, wvh,
        qh, kh, vtT, qnsT, knpk, logc);
    // 3) pipelined LDS-staged flash attention, split-K x4 (8 blocks/CU)
    attn_mfma<<<dim3(64, 16, 2), 256, 0, stream>>>(qh, kh, vtT, qnsT, knpk,
        Opart, lpart, logc, beta);
    // 4) combine partials + exp/log maps -> bf16 concat
    attn_combine<<<dim3(8192), 256, 0, stream>>>(Opart, lpart, ccb, logc);
    // 5) output projection (64x64 tiles, BK=64)
    gemm_out<<<dim3(16, 32), 256, 0, stream>>>(ccb, woh, out);
}

// Round 13
// 180.027 us; speedup vs baseline: 1.1533x; 1.0079x over previous
//
#include <hip/hip_runtime.h>
#include <math.h>

// HyperbolicMultiHeadAttention — round 13 (r12 base + attn pipeline cuts):
//  * attn: LDS double-buffer -> ONE barrier per 64-t chunk (was 2);
//    V^T staged in half-pair-interleaved t-order so PV A-frags are single
//    ds_read_b128 (was 16x ds_read_b64 + pack movs); key-norm table loads
//    hoisted above the S^T MFMAs. Math bit-identical to r12.
//  * GEMMs/split/combine: r12 verbatim (proven 181us config).
// B=2, S=1024, D=1024, H=16, dh=64.

#define EPS_ 1e-5f

constexpr int Ss = 1024, Dd = 1024, Hh = 16, DHh = 64;

typedef __attribute__((ext_vector_type(8))) short bf16x8;
typedef __attribute__((ext_vector_type(4))) short s16x4;
typedef __attribute__((ext_vector_type(4))) float f32x4;

__device__ __forceinline__ float softplusf_(float x) {
    return (x > 20.f) ? x : log1pf(expf(x));
}
__device__ __forceinline__ float waveSum64(float v) {
#pragma unroll
    for (int m = 32; m >= 1; m >>= 1) v += __shfl_xor(v, m, 64);
    return v;
}
__device__ __forceinline__ short f2bf(float f) {
    union { float f; unsigned u; } v; v.f = f;
    unsigned r = v.u + 0x7FFFu + ((v.u >> 16) & 1u);   // RNE
    return (short)(r >> 16);
}
__device__ __forceinline__ float bf2f(unsigned short h) {
    union { unsigned u; float f; } v; v.u = ((unsigned)h) << 16;
    return v.f;
}
__device__ __forceinline__ unsigned pks(short a, short b) {
    return (unsigned)(unsigned short)a | ((unsigned)(unsigned short)b << 16);
}

#if __has_builtin(__builtin_amdgcn_cvt_pk_bf16_f32)
typedef __attribute__((ext_vector_type(2))) __bf16 bfp2;
__device__ __forceinline__ unsigned cvtpk(float a, float b) {
    union { bfp2 v; unsigned u; } x;
    x.v = __builtin_amdgcn_cvt_pk_bf16_f32(a, b);
    return x.u;
}
#else
__device__ __forceinline__ unsigned cvtpk(float a, float b) { return pks(f2bf(a), f2bf(b)); }
#endif

#if __has_builtin(__builtin_amdgcn_sqrtf)
#define FSQRT __builtin_amdgcn_sqrtf
#else
#define FSQRT sqrtf
#endif
#if __has_builtin(__builtin_amdgcn_logf)
#define FLOG2 __builtin_amdgcn_logf
#else
#define FLOG2 __log2f
#endif
#if __has_builtin(__builtin_amdgcn_exp2f)
#define FEXP2 __builtin_amdgcn_exp2f
#else
#define FEXP2 exp2f
#endif

// ---------------- fp32 -> bf16 conversion (x, Wq, Wk, Wv, Wo) ----------------
__global__ __launch_bounds__(256) void split_all(
    const float* __restrict__ x,  const float* __restrict__ Wq,
    const float* __restrict__ Wk, const float* __restrict__ Wv,
    const float* __restrict__ Wo,
    short* __restrict__ xh,  short* __restrict__ wqh,
    short* __restrict__ wkh, short* __restrict__ wvh, short* __restrict__ woh)
{
    int g = blockIdx.x * 256 + threadIdx.x;
    const float* src; short* dst; int base;
    if (g < 524288)       { src = x;  dst = xh;  base = g; }
    else if (g < 786432)  { src = Wq; dst = wqh; base = g - 524288; }
    else if (g < 1048576) { src = Wk; dst = wkh; base = g - 786432; }
    else if (g < 1310720) { src = Wv; dst = wvh; base = g - 1048576; }
    else                  { src = Wo; dst = woh; base = g - 1310720; }
    float4 v = *(const float4*)(src + (size_t)base * 4);
    uint2 hp; hp.x = cvtpk(v.x, v.y); hp.y = cvtpk(v.z, v.w);
    *(uint2*)(dst + (size_t)base * 4) = hp;
}

// ------------- QKV GEMM: 64x64 tile, BK=64, 4 waves x 16 rows + fused maps -------------
__global__ __launch_bounds__(256, 6) void gemm_qkv(
    const short* __restrict__ Ap,
    const short* __restrict__ Wq, const short* __restrict__ Wk, const short* __restrict__ Wv,
    short* __restrict__ qh, short* __restrict__ kh, short* __restrict__ vtT,
    float* __restrict__ qnsT, float2* __restrict__ knpk,
    const float* __restrict__ p_logc)
{
    const int z = blockIdx.z;
    const short* Bp = (z == 0) ? Wq : (z == 1 ? Wk : Wv);
    const int K = 1024;

    __shared__ short As[64 * 72];
    __shared__ short Bs[64 * 72];

    const int tid = threadIdx.x;
    const int wv = tid >> 6, lane = tid & 63, quad = lane >> 4, l15 = lane & 15;
    const int bm = blockIdx.y * 64, bn = blockIdx.x * 64;
    const int sr = tid >> 2, sq = (tid & 3) * 16;

    const short* gA = Ap + (size_t)(bm + sr) * K + sq;
    const short* gB = Bp + (size_t)(bn + sr) * K + sq;

    f32x4 acc[4];
#pragma unroll
    for (int j = 0; j < 4; j++) acc[j] = (f32x4){0.f, 0.f, 0.f, 0.f};

    bf16x8 a0 = *(const bf16x8*)gA;
    bf16x8 a1 = *(const bf16x8*)(gA + 8);
    bf16x8 b0 = *(const bf16x8*)gB;
    bf16x8 b1 = *(const bf16x8*)(gB + 8);

    for (int k0 = 0; k0 < K; k0 += 64) {
        __syncthreads();
        *(bf16x8*)&As[sr * 72 + sq]     = a0;
        *(bf16x8*)&As[sr * 72 + sq + 8] = a1;
        *(bf16x8*)&Bs[sr * 72 + sq]     = b0;
        *(bf16x8*)&Bs[sr * 72 + sq + 8] = b1;
        __syncthreads();
        if (k0 + 64 < K) {
            a0 = *(const bf16x8*)(gA + k0 + 64);
            a1 = *(const bf16x8*)(gA + k0 + 64 + 8);
            b0 = *(const bf16x8*)(gB + k0 + 64);
            b1 = *(const bf16x8*)(gB + k0 + 64 + 8);
        }
#pragma unroll
        for (int w = 0; w < 2; w++) {
            bf16x8 fa = *(const bf16x8*)&As[(wv * 16 + l15) * 72 + w * 32 + quad * 8];
#pragma unroll
            for (int nt = 0; nt < 4; nt++) {
                bf16x8 fb = *(const bf16x8*)&Bs[(nt * 16 + l15) * 72 + w * 32 + quad * 8];
                acc[nt] = __builtin_amdgcn_mfma_f32_16x16x32_bf16(fa, fb, acc[nt], 0, 0, 0);
            }
        }
    }

    const float c = softplusf_(p_logc[0]);
    const float sc = sqrtf(c);
    const float twoC = 2.f * c;
    const int h0 = blockIdx.x;
    const int mbase = bm + wv * 16;

    if (z < 2) {
        short* yout = (z == 0) ? qh : kh;
        float fr[4];
#pragma unroll
        for (int r = 0; r < 4; r++) {
            float s2 = 0.f;
#pragma unroll
            for (int nt = 0; nt < 4; nt++) s2 += acc[nt][r] * acc[nt][r];
#pragma unroll
            for (int mk = 1; mk < 16; mk <<= 1) s2 += __shfl_xor(s2, mk, 64);
            float n = fmaxf(sqrtf(s2), EPS_);
            float fac = tanhf(sc * n) / (sc * n);
            fr[r] = fac;
            if (l15 == 0) {
                int m = mbase + quad * 4 + r;
                int bI = m >> 10, s = m & 1023;
                float yns = s2 * fac * fac;
                if (z == 0) {
                    qnsT[(size_t)(bI * Hh + h0) * Ss + s] = yns;
                } else {
                    knpk[(size_t)(bI * Hh + h0) * Ss + s]
                        = make_float2(yns, twoC / (1.f - c * yns));
                }
            }
        }
#pragma unroll
        for (int nt = 0; nt < 4; nt++)
#pragma unroll
            for (int r = 0; r < 4; r++) {
                int m = mbase + quad * 4 + r;
                yout[(size_t)m * Dd + bn + nt * 16 + l15] = f2bf(acc[nt][r] * fr[r]);
            }
    } else {
        float tr[4];
#pragma unroll
        for (int r = 0; r < 4; r++) {
            float s2 = 0.f;
#pragma unroll
            for (int nt = 0; nt < 4; nt++) s2 += acc[nt][r] * acc[nt][r];
#pragma unroll
            for (int mk = 1; mk < 16; mk <<= 1) s2 += __shfl_xor(s2, mk, 64);
            float n = fmaxf(sqrtf(s2), EPS_);
            float fac = tanhf(sc * n) / (sc * n);
            float yn = n * fac;
            float ycl = fminf(yn, 1.f / sc - EPS_);
            float f2 = atanhf(sc * ycl) / (sc * fmaxf(yn, EPS_));
            tr[r] = fac * f2;
        }
        const int m0 = mbase + quad * 4;
        const int bI = m0 >> 10, s0 = m0 & 1023;
#pragma unroll
        for (int nt = 0; nt < 4; nt++) {
            int d = nt * 16 + l15;
            uint2 pk;
            pk.x = cvtpk(acc[nt][0] * tr[0], acc[nt][1] * tr[1]);
            pk.y = cvtpk(acc[nt][2] * tr[2], acc[nt][3] * tr[3]);
            *(uint2*)&vtT[((size_t)(bI * Hh + h0) * DHh + d) * Ss + s0] = pk;
        }
    }
}

// ---------------- LDS double-buffered MFMA flash attention (split-K x4) ----------------
// One barrier per 64-t chunk. V^T staged in half-pair-interleaved t-order:
// slot(t) = (t>>5)*32 + ((t&15)>>2)*8 + ((t>>4)&1)*4 + (t&3)  -> PV A-frag
// = single ds_read_b128 at [d][quad*8] / [d][32+quad*8].
__global__ __launch_bounds__(256) void attn_mfma(
    const short* __restrict__ qh, const short* __restrict__ kh, const short* __restrict__ vtT,
    const float* __restrict__ qnsT, const float2* __restrict__ knpk,
    unsigned short* __restrict__ Opart, float* __restrict__ lpart,
    const float* __restrict__ p_logc, const float* __restrict__ p_beta)
{
    const float c = softplusf_(p_logc[0]);
    const float sc = sqrtf(c);
    const float bp = softplusf_(p_beta[0]);
    const float nkc = -bp / sc;          // p = u^(-bp/sc) = 2^(nkc * log2 u)
    const float cap = 2.f * c * 1e5f;    // = 2c / EPS-clamped denom
    const float onePlus = 1.f + EPS_;

    const int h = blockIdx.y, b = blockIdx.z;
    const int kr = blockIdx.x & 3, qt = blockIdx.x >> 2;
    const int tid = threadIdx.x;
    const int wv = tid >> 6, lane = tid & 63;
    const int quad = lane >> 4, l15 = lane & 15;
    const int bh = b * Hh + h;
    const int q = qt * 64 + wv * 16 + l15;

    __shared__ short Ks[2][64][72];   // [buf][t][d]
    __shared__ short Vt[2][64][72];   // [buf][d][permuted t]

    const short* qb = qh + (size_t)(b * Ss + q) * Dd + h * DHh + quad * 8;
    bf16x8 qf0 = *(const bf16x8*)qb;
    bf16x8 qf1 = *(const bf16x8*)(qb + 32);

    const float qn = qnsT[(size_t)bh * Ss + q];
    const float irq = 1.f / (1.f - c * qn);

    f32x4 O4[4];
#pragma unroll
    for (int nt = 0; nt < 4; nt++) O4[nt] = (f32x4){0.f, 0.f, 0.f, 0.f};
    float lac = 0.f;

    const int tbase = kr * 256;
    const int sr = tid >> 2, sseg = (tid & 3) * 16;
    const int vhi = sseg & 32;                 // slot-half base
    const int vup = (sseg & 16) ? 4 : 0;       // upper-quad offset
    const short* kgp = kh + (size_t)(b * Ss + tbase + sr) * Dd + h * DHh + sseg;
    const short* vgp = vtT + ((size_t)bh * DHh + sr) * Ss + tbase + sseg;
    const float2* nb = knpk + (size_t)bh * Ss;

    // preload + stage chunk 0 into buf 0
    bf16x8 kA0 = *(const bf16x8*)kgp;
    bf16x8 kA1 = *(const bf16x8*)(kgp + 8);
    bf16x8 vA0 = *(const bf16x8*)vgp;
    bf16x8 vA1 = *(const bf16x8*)(vgp + 8);
    {
        *(bf16x8*)&Ks[0][sr][sseg]     = kA0;
        *(bf16x8*)&Ks[0][sr][sseg + 8] = kA1;
        short* vrow = &Vt[0][sr][0];
        *(s16x4*)(vrow + vhi + vup)      = __builtin_shufflevector(vA0, vA0, 0, 1, 2, 3);
        *(s16x4*)(vrow + vhi + 8 + vup)  = __builtin_shufflevector(vA0, vA0, 4, 5, 6, 7);
        *(s16x4*)(vrow + vhi + 16 + vup) = __builtin_shufflevector(vA1, vA1, 0, 1, 2, 3);
        *(s16x4*)(vrow + vhi + 24 + vup) = __builtin_shufflevector(vA1, vA1, 4, 5, 6, 7);
    }
    __syncthreads();

    for (int ch = 0; ch < 4; ch++) {
        const int cur = ch & 1, nxt = cur ^ 1;
        const int t0 = tbase + ch * 64;

        if (ch < 3) {   // issue next-chunk global loads; land during compute
            kA0 = *(const bf16x8*)(kgp + (size_t)((ch + 1) * 64) * Dd);
            kA1 = *(const bf16x8*)(kgp + (size_t)((ch + 1) * 64) * Dd + 8);
            vA0 = *(const bf16x8*)(vgp + (ch + 1) * 64);
            vA1 = *(const bf16x8*)(vgp + (ch + 1) * 64 + 8);
        }

        // key-norm table for this chunk (hoisted above MFMAs for overlap)
        f32x4 n0[4], n1[4];
#pragma unroll
        for (int nt = 0; nt < 4; nt++) {
            const float2* np = nb + t0 + nt * 16 + quad * 4;
            n0[nt] = *(const f32x4*)np;
            n1[nt] = *(const f32x4*)(np + 2);
        }

        // S^T = K * Q^T (K A-frags from LDS buf cur)
        f32x4 acc[4];
#pragma unroll
        for (int nt = 0; nt < 4; nt++) {
            bf16x8 k0 = *(const bf16x8*)&Ks[cur][nt * 16 + l15][quad * 8];
            bf16x8 k1 = *(const bf16x8*)&Ks[cur][nt * 16 + l15][32 + quad * 8];
            f32x4 a = (f32x4){0.f, 0.f, 0.f, 0.f};
            a = __builtin_amdgcn_mfma_f32_16x16x32_bf16(k0, qf0, a, 0, 0, 0);
            a = __builtin_amdgcn_mfma_f32_16x16x32_bf16(k1, qf1, a, 0, 0, 0);
            acc[nt] = a;
        }

        // scores (lane: t = nt*16 + quad*4 + r, q = l15)
        float sv[4][4];
#pragma unroll
        for (int nt = 0; nt < 4; nt++) {
#pragma unroll
            for (int r = 0; r < 4; r++) {
                float kn   = (r < 2) ? n0[nt][(r & 1) * 2]     : n1[nt][(r & 1) * 2];
                float ik2c = (r < 2) ? n0[nt][(r & 1) * 2 + 1] : n1[nt][(r & 1) * 2 + 1];
                float dns = (qn + kn) - 2.f * acc[nt][r];
                float co  = fminf(irq * ik2c, cap);
                float arg = fmaxf(fmaf(co, dns, 1.f), onePlus);
                float u   = arg + FSQRT(fmaf(arg, arg, -1.f));
                float p   = FEXP2(nkc * FLOG2(u));
                sv[nt][r] = p;
                lac += p;
            }
        }

        union { unsigned u[4]; bf16x8 v; } p0, p1;
        p0.u[0] = cvtpk(sv[0][0], sv[0][1]); p0.u[1] = cvtpk(sv[0][2], sv[0][3]);
        p0.u[2] = cvtpk(sv[1][0], sv[1][1]); p0.u[3] = cvtpk(sv[1][2], sv[1][3]);
        p1.u[0] = cvtpk(sv[2][0], sv[2][1]); p1.u[1] = cvtpk(sv[2][2], sv[2][3]);
        p1.u[2] = cvtpk(sv[3][0], sv[3][1]); p1.u[3] = cvtpk(sv[3][2], sv[3][3]);

        // O^T += V^T * P^T (V A-frags: single b128 each, permuted layout)
#pragma unroll
        for (int nt = 0; nt < 4; nt++) {
            bf16x8 v0 = *(const bf16x8*)&Vt[cur][nt * 16 + l15][quad * 8];
            bf16x8 v1 = *(const bf16x8*)&Vt[cur][nt * 16 + l15][32 + quad * 8];
            O4[nt] = __builtin_amdgcn_mfma_f32_16x16x32_bf16(v0, p0.v, O4[nt], 0, 0, 0);
            O4[nt] = __builtin_amdgcn_mfma_f32_16x16x32_bf16(v1, p1.v, O4[nt], 0, 0, 0);
        }

        if (ch < 3) {   // stage next chunk into buf nxt; single barrier
            *(bf16x8*)&Ks[nxt][sr][sseg]     = kA0;
            *(bf16x8*)&Ks[nxt][sr][sseg + 8] = kA1;
            short* vrow = &Vt[nxt][sr][0];
            *(s16x4*)(vrow + vhi + vup)      = __builtin_shufflevector(vA0, vA0, 0, 1, 2, 3);
            *(s16x4*)(vrow + vhi + 8 + vup)  = __builtin_shufflevector(vA0, vA0, 4, 5, 6, 7);
            *(s16x4*)(vrow + vhi + 16 + vup) = __builtin_shufflevector(vA1, vA1, 0, 1, 2, 3);
            *(s16x4*)(vrow + vhi + 24 + vup) = __builtin_shufflevector(vA1, vA1, 4, 5, 6, 7);
            __syncthreads();
        }
    }

    lac += __shfl_xor(lac, 16, 64);
    lac += __shfl_xor(lac, 32, 64);
    unsigned short* ob = Opart + (((size_t)bh * 4 + kr) * Ss + q) * DHh;
#pragma unroll
    for (int nt = 0; nt < 4; nt++) {
        uint2 pk;
        pk.x = cvtpk(O4[nt][0], O4[nt][1]);
        pk.y = cvtpk(O4[nt][2], O4[nt][3]);
        *(uint2*)(ob + nt * 16 + quad * 4) = pk;
    }
    if (lane < 16)
        lpart[((size_t)bh * 4 + kr) * Ss + qt * 64 + wv * 16 + lane] = lac;
}

// ---------------- combine 4 split-K partials + exp/log-map epilogue ----------------
__global__ __launch_bounds__(256) void attn_combine(
    const unsigned short* __restrict__ Opart, const float* __restrict__ lpart,
    short* __restrict__ ccb, const float* __restrict__ p_logc)
{
    const float c = softplusf_(p_logc[0]);
    const float sc = sqrtf(c);
    const int wv = threadIdx.x >> 6, d = threadIdx.x & 63;
    const int task = blockIdx.x * 4 + wv;        // bh*1024 + s
    const int bh = task >> 10, s = task & 1023;

    float O = 0.f, l = 0.f;
#pragma unroll
    for (int k = 0; k < 4; k++) {
        O += bf2f(Opart[(((size_t)bh * 4 + k) * Ss + s) * DHh + d]);
        l += lpart[((size_t)bh * 4 + k) * Ss + s];
    }
    float ot = O / l;

    float t2 = waveSum64(ot * ot);
    float n = fmaxf(sqrtf(t2), EPS_);
    float fac = tanhf(sc * n) / (sc * n);          // exp_map
    float y2 = t2 * fac * fac;
    float yn = fmaxf(sqrtf(y2), EPS_);
    float ycl = fminf(yn, 1.f / sc - EPS_);
    float fac2 = atanhf(sc * ycl) / (sc * yn);     // log_map
    float tot = fac * fac2;

    int b = bh >> 4, hh = bh & 15;
    ccb[(size_t)(b * Ss + s) * Dd + hh * DHh + d] = f2bf(ot * tot);
}

// ---------------- output projection: 64x64 tile, BK=64 ----------------
__global__ __launch_bounds__(256, 6) void gemm_out(
    const short* __restrict__ Ap, const short* __restrict__ Bp,
    float* __restrict__ Cp)
{
    const int K = 1024, N = 1024;
    __shared__ short As[64 * 72];
    __shared__ short Bs[64 * 72];
    const int tid = threadIdx.x;
    const int wv = tid >> 6, lane = tid & 63, quad = lane >> 4, l15 = lane & 15;
    const int bm = blockIdx.y * 64, bn = blockIdx.x * 64;
    const int sr = tid >> 2, sq = (tid & 3) * 16;

    const short* gA = Ap + (size_t)(bm + sr) * K + sq;
    const short* gB = Bp + (size_t)(bn + sr) * K + sq;

    f32x4 acc[4];
#pragma unroll
    for (int j = 0; j < 4; j++) acc[j] = (f32x4){0.f, 0.f, 0.f, 0.f};

    bf16x8 a0 = *(const bf16x8*)gA;
    bf16x8 a1 = *(const bf16x8*)(gA + 8);
    bf16x8 b0 = *(const bf16x8*)gB;
    bf16x8 b1 = *(const bf16x8*)(gB + 8);

    for (int k0 = 0; k0 < K; k0 += 64) {
        __syncthreads();
        *(bf16x8*)&As[sr * 72 + sq]     = a0;
        *(bf16x8*)&As[sr * 72 + sq + 8] = a1;
        *(bf16x8*)&Bs[sr * 72 + sq]     = b0;
        *(bf16x8*)&Bs[sr * 72 + sq + 8] = b1;
        __syncthreads();
        if (k0 + 64 < K) {
            a0 = *(const bf16x8*)(gA + k0 + 64);
            a1 = *(const bf16x8*)(gA + k0 + 64 + 8);
            b0 = *(const bf16x8*)(gB + k0 + 64);
            b1 = *(const bf16x8*)(gB + k0 + 64 + 8);
        }
#pragma unroll
        for (int w = 0; w < 2; w++) {
            bf16x8 fa = *(const bf16x8*)&As[(wv * 16 + l15) * 72 + w * 32 + quad * 8];
#pragma unroll
            for (int nt = 0; nt < 4; nt++) {
                bf16x8 fb = *(const bf16x8*)&Bs[(nt * 16 + l15) * 72 + w * 32 + quad * 8];
                acc[nt] = __builtin_amdgcn_mfma_f32_16x16x32_bf16(fa, fb, acc[nt], 0, 0, 0);
            }
        }
    }
#pragma unroll
    for (int nt = 0; nt < 4; nt++)
#pragma unroll
        for (int r = 0; r < 4; r++)
            Cp[(size_t)(bm + wv * 16 + quad * 4 + r) * N + bn + nt * 16 + l15] = acc[nt][r];
}

extern "C" void kernel_launch(void* const* d_in, const int* in_sizes, int n_in,
                              void* d_out, int out_size, void* d_ws, size_t ws_size,
                              hipStream_t stream)
{
    const float* x    = (const float*)d_in[0];
    const float* Wq   = (const float*)d_in[1];
    const float* Wk   = (const float*)d_in[2];
    const float* Wv   = (const float*)d_in[3];
    const float* Wo   = (const float*)d_in[4];
    const float* logc = (const float*)d_in[5];
    const float* beta = (const float*)d_in[6];
    float* out = (float*)d_out;

    const size_t M2 = 2097152, M1 = 1048576;
    short* ws    = (short*)d_ws;
    short* xh    = ws;                 // 2M shorts (dead after gemm_qkv; ccb aliases)
    short* wqh   = xh + M2;            // 1M each
    short* wkh   = wqh + M1;
    short* wvh   = wkh + M1;
    short* woh   = wvh + M1;
    short* qh    = woh + M1;           // 2M each
    short* kh    = qh + M2;
    short* vtT   = kh + M2;
    float* qnsT  = (float*)(vtT + M2); // 32K floats
    float2* knpk = (float2*)(qnsT + 32768);   // 32K float2
    float* lpart = (float*)(knpk + 32768);    // 128K floats
    unsigned short* Opart = (unsigned short*)(lpart + 131072);  // 8M bf16 (16MB)
    short* ccb   = xh;                 // alias (xh dead after gemm_qkv)

    // 1) fp32 -> bf16
    split_all<<<dim3(6144), 256, 0, stream>>>(x, Wq, Wk, Wv, Wo, xh, wqh, wkh, wvh, woh);
    // 2) QKV projection + fused hyperbolic maps / packed key table (6 blocks/CU)
    gemm_qkv<<<dim3(16, 32, 3), 256, 0, stream>>>(xh, wqh, wkh, wvh,
        qh, kh, vtT, qnsT, knpk, logc);
    // 3) double-buffered flash attention, split-K x4
    attn_mfma<<<dim3(64, 16, 2), 256, 0, stream>>>(qh, kh, vtT, qnsT, knpk,
        Opart, lpart, logc, beta);
    // 4) combine partials + exp/log maps -> bf16 concat
    attn_combine<<<dim3(8192), 256, 0, stream>>>(Opart, lpart, ccb, logc);
    // 5) output projection (64x64 tiles, BK=64)
    gemm_out<<<dim3(16, 32), 256, 0, stream>>>(ccb, woh, out);
}